// Round 3
// baseline (248.008 us; speedup 1.0000x reference)
//
#include <hip/hip_runtime.h>
#include <math.h>

#define DEV __device__ __forceinline__

// ONE row per thread, scalar fp32, k-outer, id1+id2 parked in LDS.
//
// R2 post-mortem: de-pairing was right about the FMA floor (scalar fma 2cyc
// == pk_fma 4cyc per 2 rows) but under launch_bounds(256,4) the allocator
// kept only 36 arch VGPRs and shuttled the 57-float identity state through
// AGPRs: 87.3 busy-cyc/row vs R0's 47.9 (floor 36.6). Occupancy 57% couldn't
// pay for a 2.4x fatter stream -> 88us > 75us.
//
// R3 fix: remove the long-lived state from the register file instead of
// fighting the allocator. id1 (12f) and id2 (11f) are written at fc1/fc2 and
// read at fc13/fc12 — longest live ranges. Park them in LDS as THREAD-PRIVATE
// scratch: SoA sid[j*256+tid] -> bank tid%32, 2 lanes/bank (free), and no
// __syncthreads anywhere (each thread only touches its own slots).
// Peak reg demand drops to ~60-70 (id3..id6=34 + working set), so
// launch_bounds(256,6) (85-reg budget) fits without spills.
// LDS 23*256*4 = 23.5 KB/block -> 6 blocks/CU -> 24 waves/CU (75%).
template <int DIN, int DOUT>
DEV void lin(const float* __restrict__ w, const float* __restrict__ b,
             const float* in, float* out) {
#pragma unroll
    for (int o = 0; o < DOUT; ++o) out[o] = b[o];
#pragma unroll
    for (int k = 0; k < DIN; ++k) {
        float xk = in[k];
#pragma unroll
        for (int o = 0; o < DOUT; ++o)
            out[o] = __builtin_fmaf(xk, w[o * DIN + k], out[o]);
    }
}

// Accumulator starts at bias + skip (fuses the decoder skip-add).
template <int DIN, int DOUT>
DEV void lin_skip(const float* __restrict__ w, const float* __restrict__ b,
                  const float* in, const float* skip, float* out) {
#pragma unroll
    for (int o = 0; o < DOUT; ++o) out[o] = b[o] + skip[o];
#pragma unroll
    for (int k = 0; k < DIN; ++k) {
        float xk = in[k];
#pragma unroll
        for (int o = 0; o < DOUT; ++o)
            out[o] = __builtin_fmaf(xk, w[o * DIN + k], out[o]);
    }
}

template <int N>
DEV void relu_ip(float* v) {
#pragma unroll
    for (int k = 0; k < N; ++k) v[k] = fmaxf(v[k], 0.0f);
}

__global__ void __launch_bounds__(256, 6)
csnet14_kernel(const float* __restrict__ x,
               const float* __restrict__ w1,  const float* __restrict__ b1,
               const float* __restrict__ w2,  const float* __restrict__ b2,
               const float* __restrict__ w3,  const float* __restrict__ b3,
               const float* __restrict__ w4,  const float* __restrict__ b4,
               const float* __restrict__ w5,  const float* __restrict__ b5,
               const float* __restrict__ w6,  const float* __restrict__ b6,
               const float* __restrict__ w7,  const float* __restrict__ b7,
               const float* __restrict__ w8,  const float* __restrict__ b8,
               const float* __restrict__ w9,  const float* __restrict__ b9,
               const float* __restrict__ w10, const float* __restrict__ b10,
               const float* __restrict__ w11, const float* __restrict__ b11,
               const float* __restrict__ w12, const float* __restrict__ b12,
               const float* __restrict__ w13, const float* __restrict__ b13,
               const float* __restrict__ w14, const float* __restrict__ b14,
               float* __restrict__ out, int n) {
    // Thread-private LDS scratch: slots [0..11] = id1, [12..22] = id2.
    // SoA layout: sid[j*256 + tid] -> bank = tid%32, conflict-free.
    __shared__ float sid[23 * 256];
    const int tid = threadIdx.x;
    int t = blockIdx.x * blockDim.x + tid;
    if (t >= n) return;

    // One row: 12 contiguous floats = 3x float4 (48 B/lane, coalesced).
    const float4* xr = reinterpret_cast<const float4*>(x + (size_t)t * 12);
    float4 a0 = xr[0], a1 = xr[1], a2 = xr[2];
    float h0[12] = {a0.x, a0.y, a0.z, a0.w, a1.x, a1.y, a1.z, a1.w,
                    a2.x, a2.y, a2.z, a2.w};

    // fc1: compute in regs, ReLU, park in LDS. Reg copy stays live only
    // through fc2, then dies.
    float id1[12]; lin<12, 12>(w1, b1, h0,  id1); relu_ip<12>(id1);
#pragma unroll
    for (int j = 0; j < 12; ++j) sid[j * 256 + tid] = id1[j];

    // fc2: same, park id2.
    float id2[11]; lin<12, 11>(w2, b2, id1, id2); relu_ip<11>(id2);
#pragma unroll
    for (int j = 0; j < 11; ++j) sid[(12 + j) * 256 + tid] = id2[j];

    // fc3..fc6: identities stay in registers (34 floats, short-ish ranges).
    float id3[10]; lin<11, 10>(w3, b3, id2, id3); relu_ip<10>(id3);
    float id4[9];  lin<10,  9>(w4, b4, id3, id4); relu_ip<9>(id4);
    float id5[8];  lin< 9,  8>(w5, b5, id4, id5); relu_ip<8>(id5);
    float id6[7];  lin< 8,  7>(w6, b6, id5, id6); relu_ip<7>(id6);

    // Bottleneck fc7.
    float t7[6];   lin< 7,  6>(w7, b7, id6, t7);  relu_ip<6>(t7);

    // Decoder fc8..fc11: skips from registers.
    float t8[7];   lin_skip< 6,  7>(w8,  b8,  t7,  id6, t8);  relu_ip<7>(t8);
    float t9[8];   lin_skip< 7,  8>(w9,  b9,  t8,  id5, t9);  relu_ip<8>(t9);
    float t10[9];  lin_skip< 8,  9>(w10, b10, t9,  id4, t10); relu_ip<9>(t10);
    float t11[10]; lin_skip< 9, 10>(w11, b11, t10, id3, t11); relu_ip<10>(t11);

    // fc12: skip = id2 from LDS.
    float sk2[11];
#pragma unroll
    for (int j = 0; j < 11; ++j) sk2[j] = sid[(12 + j) * 256 + tid];
    float t12[11]; lin_skip<10, 11>(w12, b12, t11, sk2, t12); relu_ip<11>(t12);

    // fc13: skip = id1 from LDS.
    float sk1[12];
#pragma unroll
    for (int j = 0; j < 12; ++j) sk1[j] = sid[j * 256 + tid];
    float t13[12]; lin_skip<11, 12>(w13, b13, t12, sk1, t13); relu_ip<12>(t13);

    // fc14 (12 -> 2) + softmax.
    float l[2];    lin<12,  2>(w14, b14, t13, l);
    float m  = fmaxf(l[0], l[1]);
    float e0 = __expf(l[0] - m);
    float e1 = __expf(l[1] - m);
    float inv = __builtin_amdgcn_rcpf(e0 + e1);

    float2 o;  // row t -> out[2t], out[2t+1]; 8 B/lane, coalesced
    o.x = e0 * inv;
    o.y = e1 * inv;
    reinterpret_cast<float2*>(out)[t] = o;
}

extern "C" void kernel_launch(void* const* d_in, const int* in_sizes, int n_in,
                              void* d_out, int out_size, void* d_ws, size_t ws_size,
                              hipStream_t stream) {
    const float* x   = (const float*)d_in[0];
    const float* w1  = (const float*)d_in[1];  const float* b1  = (const float*)d_in[2];
    const float* w2  = (const float*)d_in[3];  const float* b2  = (const float*)d_in[4];
    const float* w3  = (const float*)d_in[5];  const float* b3  = (const float*)d_in[6];
    const float* w4  = (const float*)d_in[7];  const float* b4  = (const float*)d_in[8];
    const float* w5  = (const float*)d_in[9];  const float* b5  = (const float*)d_in[10];
    const float* w6  = (const float*)d_in[11]; const float* b6  = (const float*)d_in[12];
    const float* w7  = (const float*)d_in[13]; const float* b7  = (const float*)d_in[14];
    const float* w8  = (const float*)d_in[15]; const float* b8  = (const float*)d_in[16];
    const float* w9  = (const float*)d_in[17]; const float* b9  = (const float*)d_in[18];
    const float* w10 = (const float*)d_in[19]; const float* b10 = (const float*)d_in[20];
    const float* w11 = (const float*)d_in[21]; const float* b11 = (const float*)d_in[22];
    const float* w12 = (const float*)d_in[23]; const float* b12 = (const float*)d_in[24];
    const float* w13 = (const float*)d_in[25]; const float* b13 = (const float*)d_in[26];
    const float* w14 = (const float*)d_in[27]; const float* b14 = (const float*)d_in[28];
    float* out = (float*)d_out;

    const int n = in_sizes[0] / 12;  // 2,000,000 rows
    dim3 block(256);
    dim3 grid((n + 255) / 256);
    csnet14_kernel<<<grid, block, 0, stream>>>(
        x, w1, b1, w2, b2, w3, b3, w4, b4, w5, b5, w6, b6, w7, b7,
        w8, b8, w9, b9, w10, b10, w11, b11, w12, b12, w13, b13, w14, b14,
        out, n);
}

// Round 4
// 225.221 us; speedup vs baseline: 1.1012x; 1.1012x over previous
//
#include <hip/hip_runtime.h>
#include <math.h>

#define DEV __device__ __forceinline__

// Packed fp32 pair: .x = row A, .y = row B -> v_pk_fma_f32 (2 rows/inst).
typedef float f2 __attribute__((ext_vector_type(2)));

DEV f2 splat(float s) { f2 r; r.x = s; r.y = s; return r; }

// R4 analysis: R0 (pair+pk, 75us) has a LEAN stream (6.2k busy cyc/wave vs
// 4.7k FMA floor) but waves wait 82% of their lifetime. Cause: k-outer
// consumption reads weights o-strided -> ~1186 UNMERGED s_load_dword per
// wave (SGPR budget 102 forbids whole-matrix preload) ~= 0.4 scalar
// transactions/cyc/CU = scalar-cache service rate. De-paired variants
// (R1/R3: 87 busy cyc/row vs R0 48) are dead ends: arch-VGPR starvation
// fattens the stream 2.4x.
//
// R4 fix: o-TILE (4 rows) + k-inner. Per tile, preload the contiguous
// 4xDIN weight block (<=48 floats, SGPR-resident; tile offset always 16-B
// aligned since ot%4==0) -> merges into s_load_dwordx4/x8/x16. ~4-8x fewer
// SMEM transactions; tile granularity lets the scheduler prefetch tile t+1
// under tile t's FMAs. Per-accumulator FMA order unchanged (k ascending)
// -> numerics identical to R0.
template <int DIN, int DOUT>
DEV void lin2(const float* __restrict__ w, const float* __restrict__ b,
              const f2* in, f2* out) {
    const float* __restrict__ wa = (const float*)__builtin_assume_aligned(w, 16);
#pragma unroll
    for (int ot = 0; ot < DOUT; ot += 4) {
        const int oe = (ot + 4 < DOUT) ? (ot + 4) : DOUT;
        // Contiguous uniform preload -> wide s_load merge (SGPRs).
        float wt[48];
#pragma unroll
        for (int i = 0; i < 48; ++i) {
            if (i < (oe - ot) * DIN) wt[i] = wa[ot * DIN + i];
        }
#pragma unroll
        for (int o = ot; o < oe; ++o) out[o] = splat(b[o]);
#pragma unroll
        for (int k = 0; k < DIN; ++k) {
            f2 xk = in[k];
#pragma unroll
            for (int o = ot; o < oe; ++o)
                out[o] = __builtin_elementwise_fma(
                    xk, splat(wt[(o - ot) * DIN + k]), out[o]);
        }
    }
}

// Same, but accumulator starts at bias + skip (fuses the decoder skip-add).
template <int DIN, int DOUT>
DEV void lin2_skip(const float* __restrict__ w, const float* __restrict__ b,
                   const f2* in, const f2* skip, f2* out) {
    const float* __restrict__ wa = (const float*)__builtin_assume_aligned(w, 16);
#pragma unroll
    for (int ot = 0; ot < DOUT; ot += 4) {
        const int oe = (ot + 4 < DOUT) ? (ot + 4) : DOUT;
        float wt[48];
#pragma unroll
        for (int i = 0; i < 48; ++i) {
            if (i < (oe - ot) * DIN) wt[i] = wa[ot * DIN + i];
        }
#pragma unroll
        for (int o = ot; o < oe; ++o) out[o] = splat(b[o]) + skip[o];
#pragma unroll
        for (int k = 0; k < DIN; ++k) {
            f2 xk = in[k];
#pragma unroll
            for (int o = ot; o < oe; ++o)
                out[o] = __builtin_elementwise_fma(
                    xk, splat(wt[(o - ot) * DIN + k]), out[o]);
        }
    }
}

template <int N>
DEV void relu_ip(f2* v) {
#pragma unroll
    for (int k = 0; k < N; ++k) v[k] = __builtin_elementwise_max(v[k], splat(0.0f));
}

__global__ void __launch_bounds__(256, 2)
csnet14_kernel(const float* __restrict__ x,
               const float* __restrict__ w1,  const float* __restrict__ b1,
               const float* __restrict__ w2,  const float* __restrict__ b2,
               const float* __restrict__ w3,  const float* __restrict__ b3,
               const float* __restrict__ w4,  const float* __restrict__ b4,
               const float* __restrict__ w5,  const float* __restrict__ b5,
               const float* __restrict__ w6,  const float* __restrict__ b6,
               const float* __restrict__ w7,  const float* __restrict__ b7,
               const float* __restrict__ w8,  const float* __restrict__ b8,
               const float* __restrict__ w9,  const float* __restrict__ b9,
               const float* __restrict__ w10, const float* __restrict__ b10,
               const float* __restrict__ w11, const float* __restrict__ b11,
               const float* __restrict__ w12, const float* __restrict__ b12,
               const float* __restrict__ w13, const float* __restrict__ b13,
               const float* __restrict__ w14, const float* __restrict__ b14,
               float* __restrict__ out, int nt) {
    int t = blockIdx.x * blockDim.x + threadIdx.x;
    if (t >= nt) return;  // nt = n/2 row-pairs

    // Two adjacent rows: 24 contiguous floats = 6x float4 (96 B).
    const float4* xr = reinterpret_cast<const float4*>(x + (size_t)t * 24);
    float4 a0 = xr[0], a1 = xr[1], a2 = xr[2];
    float4 a3 = xr[3], a4 = xr[4], a5 = xr[5];
    float r0[12] = {a0.x, a0.y, a0.z, a0.w, a1.x, a1.y, a1.z, a1.w,
                    a2.x, a2.y, a2.z, a2.w};
    float r1[12] = {a3.x, a3.y, a3.z, a3.w, a4.x, a4.y, a4.z, a4.w,
                    a5.x, a5.y, a5.z, a5.w};
    f2 h0[12];
#pragma unroll
    for (int k = 0; k < 12; ++k) { h0[k].x = r0[k]; h0[k].y = r1[k]; }

    // Encoder: fc1..fc6, save post-ReLU identities.
    f2 id1[12]; lin2<12, 12>(w1, b1, h0,  id1); relu_ip<12>(id1);
    f2 id2[11]; lin2<12, 11>(w2, b2, id1, id2); relu_ip<11>(id2);
    f2 id3[10]; lin2<11, 10>(w3, b3, id2, id3); relu_ip<10>(id3);
    f2 id4[9];  lin2<10,  9>(w4, b4, id3, id4); relu_ip<9>(id4);
    f2 id5[8];  lin2< 9,  8>(w5, b5, id4, id5); relu_ip<8>(id5);
    f2 id6[7];  lin2< 8,  7>(w6, b6, id5, id6); relu_ip<7>(id6);

    // Bottleneck fc7.
    f2 t7[6];   lin2< 7,  6>(w7, b7, id6, t7);  relu_ip<6>(t7);

    // Decoder: fc8..fc13, skip fused into accumulator init.
    f2 t8[7];   lin2_skip< 6,  7>(w8,  b8,  t7,  id6, t8);  relu_ip<7>(t8);
    f2 t9[8];   lin2_skip< 7,  8>(w9,  b9,  t8,  id5, t9);  relu_ip<8>(t9);
    f2 t10[9];  lin2_skip< 8,  9>(w10, b10, t9,  id4, t10); relu_ip<9>(t10);
    f2 t11[10]; lin2_skip< 9, 10>(w11, b11, t10, id3, t11); relu_ip<10>(t11);
    f2 t12[11]; lin2_skip<10, 11>(w12, b12, t11, id2, t12); relu_ip<11>(t12);
    f2 t13[12]; lin2_skip<11, 12>(w13, b13, t12, id1, t13); relu_ip<12>(t13);

    // fc14 (12 -> 2) + softmax, both rows.
    f2 l[2];    lin2<12,  2>(w14, b14, t13, l);
    f2 m  = __builtin_elementwise_max(l[0], l[1]);
    f2 d0 = l[0] - m;
    f2 d1 = l[1] - m;
    float e0a = __expf(d0.x), e0b = __expf(d0.y);
    float e1a = __expf(d1.x), e1b = __expf(d1.y);
    float inva = __builtin_amdgcn_rcpf(e0a + e1a);
    float invb = __builtin_amdgcn_rcpf(e0b + e1b);

    float4 o;  // rows 2t, 2t+1 -> out[4t..4t+3], coalesced 16 B/lane
    o.x = e0a * inva;
    o.y = e1a * inva;
    o.z = e0b * invb;
    o.w = e1b * invb;
    reinterpret_cast<float4*>(out)[t] = o;
}

extern "C" void kernel_launch(void* const* d_in, const int* in_sizes, int n_in,
                              void* d_out, int out_size, void* d_ws, size_t ws_size,
                              hipStream_t stream) {
    const float* x   = (const float*)d_in[0];
    const float* w1  = (const float*)d_in[1];  const float* b1  = (const float*)d_in[2];
    const float* w2  = (const float*)d_in[3];  const float* b2  = (const float*)d_in[4];
    const float* w3  = (const float*)d_in[5];  const float* b3  = (const float*)d_in[6];
    const float* w4  = (const float*)d_in[7];  const float* b4  = (const float*)d_in[8];
    const float* w5  = (const float*)d_in[9];  const float* b5  = (const float*)d_in[10];
    const float* w6  = (const float*)d_in[11]; const float* b6  = (const float*)d_in[12];
    const float* w7  = (const float*)d_in[13]; const float* b7  = (const float*)d_in[14];
    const float* w8  = (const float*)d_in[15]; const float* b8  = (const float*)d_in[16];
    const float* w9  = (const float*)d_in[17]; const float* b9  = (const float*)d_in[18];
    const float* w10 = (const float*)d_in[19]; const float* b10 = (const float*)d_in[20];
    const float* w11 = (const float*)d_in[21]; const float* b11 = (const float*)d_in[22];
    const float* w12 = (const float*)d_in[23]; const float* b12 = (const float*)d_in[24];
    const float* w13 = (const float*)d_in[25]; const float* b13 = (const float*)d_in[26];
    const float* w14 = (const float*)d_in[27]; const float* b14 = (const float*)d_in[28];
    float* out = (float*)d_out;

    const int n  = in_sizes[0] / 12;  // 2,000,000 rows (even)
    const int nt = n / 2;             // row-pairs
    dim3 block(256);
    dim3 grid((nt + 255) / 256);
    csnet14_kernel<<<grid, block, 0, stream>>>(
        x, w1, b1, w2, b2, w3, b3, w4, b4, w5, b5, w6, b6, w7, b7,
        w8, b8, w9, b9, w10, b10, w11, b11, w12, b12, w13, b13, w14, b14,
        out, nt);
}